// Round 3
// baseline (81.028 us; speedup 1.0000x reference)
//
#include <hip/hip_runtime.h>

#define N_TOTAL   4096
#define N_NODES   1024
#define N_MARBLES 3072
#define N_EATERS  64
#define EPS       1e-6f
#define BLOCK     256
#define JCHUNK    64                  // j's per force block
#define JCHUNKS   (N_TOTAL / JCHUNK) // 64

// ---------------------------------------------------------------------------
// Kernel 1: partial accelerations.
// grid = (16, 64), block = 256. Each block: 256 i's x 64 j's. j is
// wave-uniform -> scalar loads, no LDS. d2==0 pairs contribute exactly 0
// (dx=dy=0, finite w), so no mask needed.
// ---------------------------------------------------------------------------
__global__ __launch_bounds__(BLOCK) void force_partial(
    const float* __restrict__ pos, const float* __restrict__ mass,
    float2* __restrict__ partial)
{
    const int i  = blockIdx.x * BLOCK + threadIdx.x;
    const int j0 = blockIdx.y * JCHUNK;

    const float pxi = pos[i * 2 + 0];
    const float pyi = pos[i * 2 + 1];
    float ax = 0.f, ay = 0.f;

#pragma unroll 16
    for (int j = j0; j < j0 + JCHUNK; ++j) {
        const float dx = pos[j * 2 + 0] - pxi;   // uniform index -> s_load
        const float dy = pos[j * 2 + 1] - pyi;
        const float t  = fmaf(dx, dx, fmaf(dy, dy, EPS));  // d2 + EPS
        const float r  = rsqrtf(t);
        const float w  = r * r * r * mass[j];    // m_j * t^{-1.5}
        ax = fmaf(w, dx, ax);
        ay = fmaf(w, dy, ay);
    }

    partial[blockIdx.y * N_TOTAL + i] = make_float2(ax, ay);
}

// Shared integrate helper — MUST be the same instruction sequence for the
// main path and the redundant eater recompute so positions match exactly.
__device__ __forceinline__ float4 integrate_one(
    const float* __restrict__ pos, const float* __restrict__ vel,
    const float2* __restrict__ partial, float dt, int i)
{
    float ax = 0.f, ay = 0.f;
#pragma unroll 16
    for (int jc = 0; jc < JCHUNKS; ++jc) {
        const float2 p = partial[jc * N_TOTAL + i];
        ax += p.x;
        ay += p.y;
    }
    const float vx = vel[i * 2 + 0] + ax * dt;
    const float vy = vel[i * 2 + 1] + ay * dt;
    const float px = pos[i * 2 + 0] + vx * dt;
    const float py = pos[i * 2 + 1] + vy * dt;
    return make_float4(px, py, vx, vy);
}

// ---------------------------------------------------------------------------
// Kernel 2: fused integrate + eaten. grid = 16 blocks x 256 threads.
// Blocks 4..15 hold marbles; they redundantly recompute the 64 eaters'
// pos_new from the partials (32 KB/block of extra reads) into LDS, then
// each marble thread scans the 64 eaters. Blocks 0..3 (nodes only) skip it.
// ---------------------------------------------------------------------------
__global__ __launch_bounds__(BLOCK) void integrate_eaten(
    const float* __restrict__ pos, const float* __restrict__ vel,
    const float2* __restrict__ partial, const float* __restrict__ dtp,
    const int* __restrict__ eater_idx, const float* __restrict__ eater_radius,
    float* __restrict__ out)
{
    __shared__ float ex[N_EATERS], ey[N_EATERS], er2[N_EATERS];

    const int i  = blockIdx.x * BLOCK + threadIdx.x;
    const float dt = dtp[0];

    // Main integrate for this thread's particle.
    const float4 s = integrate_one(pos, vel, partial, dt, i);
    out[i * 2 + 0] = s.x;                       // pos_new
    out[i * 2 + 1] = s.y;
    out[2 * N_TOTAL + i * 2 + 0] = s.z;         // vel_new
    out[2 * N_TOTAL + i * 2 + 1] = s.w;

    if (blockIdx.x >= N_NODES / BLOCK) {        // marble blocks only
        if (threadIdx.x < N_EATERS) {
            const int e   = threadIdx.x;
            const int idx = eater_idx[e];
            const float4 se = integrate_one(pos, vel, partial, dt, idx);
            ex[e] = se.x;
            ey[e] = se.y;
            const float r = eater_radius[e];
            er2[e] = r * r;
        }
        __syncthreads();

        const int m = i - N_NODES;              // marble index in [0, 3072)
        bool any = false;
#pragma unroll
        for (int e = 0; e < N_EATERS; ++e) {
            const float dx = s.x - ex[e];
            const float dy = s.y - ey[e];
            any = any || (dx * dx + dy * dy <= er2[e]);
        }
        out[4 * N_TOTAL + m] = any ? 1.0f : 0.0f;
    }
}

extern "C" void kernel_launch(void* const* d_in, const int* in_sizes, int n_in,
                              void* d_out, int out_size, void* d_ws, size_t ws_size,
                              hipStream_t stream) {
    const float* pos  = (const float*)d_in[0];   // (4096, 2)
    const float* vel  = (const float*)d_in[1];   // (4096, 2)
    const float* mass = (const float*)d_in[2];   // (4096,)
    const int*   eidx = (const int*)d_in[3];     // (64,)
    const float* erad = (const float*)d_in[4];   // (64,)
    const float* dt   = (const float*)d_in[5];   // (1,)

    float* out      = (float*)d_out;             // 16384 state + 3072 eaten
    float2* partial = (float2*)d_ws;             // 64*4096 float2 = 2 MB

    dim3 g1(N_TOTAL / BLOCK, JCHUNKS);           // (16, 64)
    force_partial<<<g1, BLOCK, 0, stream>>>(pos, mass, partial);
    integrate_eaten<<<N_TOTAL / BLOCK, BLOCK, 0, stream>>>(
        pos, vel, partial, dt, eidx, erad, out);
}

// Round 4
// 78.006 us; speedup vs baseline: 1.0387x; 1.0387x over previous
//
#include <hip/hip_runtime.h>

#define N_TOTAL   4096
#define N_NODES   1024
#define N_MARBLES 3072
#define N_EATERS  64
#define EPS       1e-6f
#define BLOCK     256
#define JCHUNK    64                  // j's per force block
#define JCHUNKS   (N_TOTAL / JCHUNK) // 64

// ---------------------------------------------------------------------------
// Kernel 1: partial accelerations.
// grid = (16, 64), block = 256. Each block: 256 i's x 64 j's. j is
// wave-uniform -> scalar loads, no LDS. d2==0 pairs contribute exactly 0
// (dx=dy=0, finite w), so no mask needed.
// ---------------------------------------------------------------------------
__global__ __launch_bounds__(BLOCK) void force_partial(
    const float* __restrict__ pos, const float* __restrict__ mass,
    float2* __restrict__ partial)
{
    const int i  = blockIdx.x * BLOCK + threadIdx.x;
    const int j0 = blockIdx.y * JCHUNK;

    const float pxi = pos[i * 2 + 0];
    const float pyi = pos[i * 2 + 1];
    float ax = 0.f, ay = 0.f;

#pragma unroll 16
    for (int j = j0; j < j0 + JCHUNK; ++j) {
        const float dx = pos[j * 2 + 0] - pxi;   // uniform index -> s_load
        const float dy = pos[j * 2 + 1] - pyi;
        const float t  = fmaf(dx, dx, fmaf(dy, dy, EPS));  // d2 + EPS
        const float r  = rsqrtf(t);
        const float w  = r * r * r * mass[j];    // m_j * t^{-1.5}
        ax = fmaf(w, dx, ax);
        ay = fmaf(w, dy, ay);
    }

    partial[blockIdx.y * N_TOTAL + i] = make_float2(ax, ay);
}

// ---------------------------------------------------------------------------
// Kernel 2: integrate. grid = 64 blocks x 256 threads; each block owns 64
// particles. Wave t (of 4) sums partial chunks [16t, 16t+16) for all 64
// particles with coalesced float2 reads; LDS-reduce 4 -> 1; wave 0 does the
// Euler step and writes state_new = [pos_new; vel_new].
// ---------------------------------------------------------------------------
__global__ __launch_bounds__(BLOCK) void integrate(
    const float* __restrict__ pos, const float* __restrict__ vel,
    const float2* __restrict__ partial, const float* __restrict__ dtp,
    float* __restrict__ out)
{
    __shared__ float2 red[4][64];

    const int lane = threadIdx.x & 63;          // particle within block
    const int w    = threadIdx.x >> 6;          // wave id 0..3
    const int i    = blockIdx.x * 64 + lane;

    float ax = 0.f, ay = 0.f;
#pragma unroll 16
    for (int jc = w * 16; jc < w * 16 + 16; ++jc) {
        const float2 p = partial[jc * N_TOTAL + i];
        ax += p.x;
        ay += p.y;
    }
    red[w][lane] = make_float2(ax, ay);
    __syncthreads();

    if (w == 0) {
        const float2 r1 = red[1][lane];
        const float2 r2 = red[2][lane];
        const float2 r3 = red[3][lane];
        ax += r1.x + r2.x + r3.x;
        ay += r1.y + r2.y + r3.y;

        const float dt = dtp[0];
        const float vx = vel[i * 2 + 0] + ax * dt;
        const float vy = vel[i * 2 + 1] + ay * dt;
        const float px = pos[i * 2 + 0] + vx * dt;
        const float py = pos[i * 2 + 1] + vy * dt;

        out[i * 2 + 0] = px;                    // pos_new
        out[i * 2 + 1] = py;
        out[2 * N_TOTAL + i * 2 + 0] = vx;      // vel_new
        out[2 * N_TOTAL + i * 2 + 1] = vy;
    }
}

// ---------------------------------------------------------------------------
// Kernel 3: marble-vs-eater proximity. Reads pos_new from out (same stream ->
// ordered after integrate). Writes 1.0/0.0 at out + 4*N_TOTAL.
// ---------------------------------------------------------------------------
__global__ __launch_bounds__(BLOCK) void eaten_kernel(
    const float* __restrict__ out_state, const int* __restrict__ eater_idx,
    const float* __restrict__ eater_radius, float* __restrict__ out_eaten)
{
    __shared__ float ex[N_EATERS], ey[N_EATERS], er2[N_EATERS];
    if (threadIdx.x < N_EATERS) {
        const int idx = eater_idx[threadIdx.x];
        ex[threadIdx.x] = out_state[idx * 2 + 0];
        ey[threadIdx.x] = out_state[idx * 2 + 1];
        const float r = eater_radius[threadIdx.x];
        er2[threadIdx.x] = r * r;
    }
    __syncthreads();

    const int m = blockIdx.x * blockDim.x + threadIdx.x;
    const float mx = out_state[(N_NODES + m) * 2 + 0];
    const float my = out_state[(N_NODES + m) * 2 + 1];

    bool any = false;
#pragma unroll
    for (int e = 0; e < N_EATERS; ++e) {
        const float dx = mx - ex[e];
        const float dy = my - ey[e];
        any = any || (dx * dx + dy * dy <= er2[e]);
    }
    out_eaten[m] = any ? 1.0f : 0.0f;
}

extern "C" void kernel_launch(void* const* d_in, const int* in_sizes, int n_in,
                              void* d_out, int out_size, void* d_ws, size_t ws_size,
                              hipStream_t stream) {
    const float* pos  = (const float*)d_in[0];   // (4096, 2)
    const float* vel  = (const float*)d_in[1];   // (4096, 2)
    const float* mass = (const float*)d_in[2];   // (4096,)
    const int*   eidx = (const int*)d_in[3];     // (64,)
    const float* erad = (const float*)d_in[4];   // (64,)
    const float* dt   = (const float*)d_in[5];   // (1,)

    float* out      = (float*)d_out;             // 16384 state + 3072 eaten
    float2* partial = (float2*)d_ws;             // 64*4096 float2 = 2 MB

    dim3 g1(N_TOTAL / BLOCK, JCHUNKS);           // (16, 64)
    force_partial<<<g1, BLOCK, 0, stream>>>(pos, mass, partial);
    integrate<<<N_TOTAL / 64, BLOCK, 0, stream>>>(pos, vel, partial, dt, out);
    eaten_kernel<<<N_MARBLES / BLOCK, BLOCK, 0, stream>>>(out, eidx, erad,
                                                          out + 4 * N_TOTAL);
}